// Round 3
// baseline (337.989 us; speedup 1.0000x reference)
//
#include <hip/hip_runtime.h>

#define QK_SCALE 0.17677669529663687f
#define HREG 6528      // shorts per head region
#define KOFF 2560      // k: 64 x 40 (q: 64 x 40 at 0)
#define VOFF 4352      // vT: 32 x 68 (P: 64 x 68 at 0, overlays dead q+k)
#define XP   136       // xs/ao pitch in shorts

typedef __attribute__((ext_vector_type(8))) short bf16x8;
typedef __attribute__((ext_vector_type(4))) short bf16x4;
typedef __attribute__((ext_vector_type(4))) float floatx4;

__device__ __forceinline__ unsigned short f2bf(float f) {
    unsigned int u = __float_as_uint(f);
    u += 0x7fffu + ((u >> 16) & 1u);   // round-to-nearest-even
    return (unsigned short)(u >> 16);
}

__device__ __forceinline__ bf16x8 ld8_2x4(const short* p) {  // 8B-aligned pair load
    union { bf16x8 v8; bf16x4 v4[2]; } u;
    u.v4[0] = *(const bf16x4*)p;
    u.v4[1] = *(const bf16x4*)(p + 4);
    return u.v8;
}

// ---- prep: bf16 weights + combined (mask + gathered rel-pos bias) table ----
// ws: [0,131072) qkv_w bf16 (49152 elems) then proj_w bf16 (16384 elems)
//     [131072,...) cm fp32 (64,4,49,49)
__global__ __launch_bounds__(256) void prep_kernel(
    const float* __restrict__ qkv_w, const float* __restrict__ proj_w,
    const float* __restrict__ bias_table, const float* __restrict__ mask,
    unsigned short* __restrict__ wbf, float* __restrict__ cm)
{
    const int blk = blockIdx.x;
    if (blk < 64) {
        const int g = (blk * 256 + threadIdx.x) * 4;     // 0..65532
        float4 v = (g < 49152) ? *(const float4*)(qkv_w + g)
                               : *(const float4*)(proj_w + (g - 49152));
        ushort4 u;
        u.x = f2bf(v.x); u.y = f2bf(v.y); u.z = f2bf(v.z); u.w = f2bf(v.w);
        *(ushort4*)(wbf + g) = u;
    } else {
        const int rid = (blk - 64) * 4 + (threadIdx.x >> 6);   // 0..12543 = (w*4+h)*49+i
        const int j = threadIdx.x & 63;
        if (j < 49) {
            const int i  = rid % 49;
            const int hw = rid / 49;
            const int h  = hw & 3;
            const int wn = hw >> 2;
            const int idx = (i / 7 - j / 7 + 6) * 13 + (i % 7 - j % 7 + 6);
            cm[rid * 49 + j] = mask[wn * 2401 + i * 49 + j] + bias_table[idx * 4 + h];
        }
    }
}

// LDS (shorts): head h base hq = h*6528:
//   phase A: q [hq, hq+2560) pitch 40; k [hq+2560, hq+5120) pitch 40
//   phase B: P [hq, hq+4352) pitch 68; vT [hq+4352, hq+6528) pitch 68 (32 rows)
// xs/ao: [0, 8704) pitch 136 — time-sliced vs head regions via barriers.
__global__ __launch_bounds__(256, 3) void winattn_mfma(
    const float* __restrict__ x,
    const float* __restrict__ qkv_b,
    const float* __restrict__ proj_b,
    const unsigned short* __restrict__ wbf,
    const float* __restrict__ cm,
    float* __restrict__ out)
{
    __shared__ __align__(16) short smem[26112];   // 52224 B -> 3 blocks/CU

    const int tid  = threadIdx.x;
    const int lane = tid & 63;
    const int lid  = lane & 15;
    const int quad = lane >> 4;
    const int h    = tid >> 6;        // wave = head
    const int b    = blockIdx.x;
    const int w    = b & 63;
    const int hq   = h * HREG;

    // ---- Phase 0: stage x (49x128) fp32 -> bf16 LDS (pitch 136), pad rows zeroed ----
    {
        const float4* xg = (const float4*)(x + (size_t)b * 6272);
        for (int i = tid; i < 1568; i += 256) {       // 49*32 float4s
            int n = i >> 5, c4 = i & 31;
            float4 v = xg[i];
            ushort4 u;
            u.x = f2bf(v.x); u.y = f2bf(v.y); u.z = f2bf(v.z); u.w = f2bf(v.w);
            *(ushort4*)&smem[n * XP + c4 * 4] = u;
        }
        ushort4 z; z.x = 0; z.y = 0; z.z = 0; z.w = 0;
        for (int i = tid; i < 510; i += 256)          // rows 49..63
            *(ushort4*)&smem[49 * XP + i * 4] = z;
    }
    __syncthreads();

    // ---- full A tile (64x128) into registers ----
    bf16x8 ax[4][4];
    #pragma unroll
    for (int mt = 0; mt < 4; ++mt)
        #pragma unroll
        for (int kb = 0; kb < 4; ++kb)
            ax[mt][kb] = *(const bf16x8*)&smem[(mt * 16 + lid) * XP + kb * 32 + quad * 8];
    __syncthreads();   // xs consumed; head regions writable

    const floatx4 z4 = {0.f, 0.f, 0.f, 0.f};

    // ---- q,k only (t=0..3): wave h -> cols [32h,32h+32) ----
    #pragma unroll
    for (int t = 0; t < 4; ++t) {
        const int cb = (t < 2) ? (h * 32 + t * 16) : (128 + h * 32 + (t - 2) * 16);
        const unsigned short* wr = wbf + (size_t)(cb + lid) * 128 + quad * 8;
        floatx4 acc[4] = {z4, z4, z4, z4};
        #pragma unroll
        for (int kb = 0; kb < 4; ++kb) {
            bf16x8 bw = *(const bf16x8*)(wr + kb * 32);
            #pragma unroll
            for (int mt = 0; mt < 4; ++mt)
                acc[mt] = __builtin_amdgcn_mfma_f32_16x16x32_bf16(ax[mt][kb], bw, acc[mt], 0, 0, 0);
        }
        const float bias = qkv_b[cb + lid];
        #pragma unroll
        for (int mt = 0; mt < 4; ++mt)
            #pragma unroll
            for (int r = 0; r < 4; ++r) {
                const int row = mt * 16 + quad * 4 + r;
                const float v = acc[mt][r] + bias;
                if (t < 2)  smem[hq + row * 40 + t * 16 + lid] = (short)f2bf(v * QK_SCALE);
                else        smem[hq + KOFF + row * 40 + (t - 2) * 16 + lid] = (short)f2bf(v);
            }
    }

    // ---- S = q @ k^T, cm folded in as MFMA C operand ----
    bf16x8 aq[4], bk[4];
    #pragma unroll
    for (int mt = 0; mt < 4; ++mt)
        aq[mt] = ld8_2x4(&smem[hq + (mt * 16 + lid) * 40 + quad * 8]);
    #pragma unroll
    for (int nt = 0; nt < 4; ++nt)
        bk[nt] = ld8_2x4(&smem[hq + KOFF + (nt * 16 + lid) * 40 + quad * 8]);

    const float* cmb = cm + (size_t)(w * 4 + h) * 2401;
    floatx4 sacc[4][4];
    #pragma unroll
    for (int mt = 0; mt < 4; ++mt) {
        const int r0 = mt * 16 + quad * 4;
        #pragma unroll
        for (int nt = 0; nt < 4; ++nt) {
            const int col  = nt * 16 + lid;
            const int colc = (col < 49) ? col : 48;
            floatx4 ci;
            #pragma unroll
            for (int r = 0; r < 4; ++r) {
                const int rowc = (r0 + r < 49) ? (r0 + r) : 48;
                ci[r] = cmb[rowc * 49 + colc];
            }
            sacc[mt][nt] = __builtin_amdgcn_mfma_f32_16x16x32_bf16(aq[mt], bk[nt], ci, 0, 0, 0);
        }
    }

    // ---- deferred v (t=4,5): ax dies here; vT into [VOFF,VOFF+2176) pitch 68 ----
    #pragma unroll
    for (int tv = 0; tv < 2; ++tv) {
        const int cb = 256 + h * 32 + tv * 16;
        const unsigned short* wr = wbf + (size_t)(cb + lid) * 128 + quad * 8;
        floatx4 acc[4] = {z4, z4, z4, z4};
        #pragma unroll
        for (int kb = 0; kb < 4; ++kb) {
            bf16x8 bw = *(const bf16x8*)(wr + kb * 32);
            #pragma unroll
            for (int mt = 0; mt < 4; ++mt)
                acc[mt] = __builtin_amdgcn_mfma_f32_16x16x32_bf16(ax[mt][kb], bw, acc[mt], 0, 0, 0);
        }
        const float bias = qkv_b[cb + lid];
        #pragma unroll
        for (int mt = 0; mt < 4; ++mt)
            #pragma unroll
            for (int r = 0; r < 4; ++r) {
                const int row = mt * 16 + quad * 4 + r;
                smem[hq + VOFF + (tv * 16 + lid) * 68 + row] = (short)f2bf(acc[mt][r] + bias);
            }
    }

    // ---- softmax in C-layout; write P (bf16, pitch 68) over dead q/k ----
    float invs[4][4];
    #pragma unroll
    for (int mt = 0; mt < 4; ++mt) {
        #pragma unroll
        for (int r = 0; r < 4; ++r) {
            const int row = mt * 16 + quad * 4 + r;
            float sv[4];
            #pragma unroll
            for (int nt = 0; nt < 4; ++nt) {
                const int col = nt * 16 + lid;
                sv[nt] = (col < 49) ? sacc[mt][nt][r] : -1e30f;
            }
            float mx = fmaxf(fmaxf(sv[0], sv[1]), fmaxf(sv[2], sv[3]));
            #pragma unroll
            for (int d = 1; d < 16; d <<= 1) mx = fmaxf(mx, __shfl_xor(mx, d));
            float sum = 0.f;
            #pragma unroll
            for (int nt = 0; nt < 4; ++nt) { float p = __expf(sv[nt] - mx); sv[nt] = p; sum += p; }
            #pragma unroll
            for (int d = 1; d < 16; d <<= 1) sum += __shfl_xor(sum, d);
            invs[mt][r] = 1.f / sum;
            #pragma unroll
            for (int nt = 0; nt < 4; ++nt)
                smem[hq + row * 68 + nt * 16 + lid] = (short)f2bf(sv[nt]);
        }
    }

    // ---- O = P @ v ----
    bf16x8 bv[2][2];
    #pragma unroll
    for (int nt2 = 0; nt2 < 2; ++nt2)
        #pragma unroll
        for (int kb2 = 0; kb2 < 2; ++kb2)
            bv[nt2][kb2] = ld8_2x4(&smem[hq + VOFF + (nt2 * 16 + lid) * 68 + kb2 * 32 + quad * 8]);

    floatx4 oacc[4][2] = {{z4, z4}, {z4, z4}, {z4, z4}, {z4, z4}};
    #pragma unroll
    for (int mt = 0; mt < 4; ++mt) {
        #pragma unroll
        for (int kb2 = 0; kb2 < 2; ++kb2) {
            bf16x8 ap = ld8_2x4(&smem[hq + (mt * 16 + lid) * 68 + kb2 * 32 + quad * 8]);
            #pragma unroll
            for (int nt2 = 0; nt2 < 2; ++nt2)
                oacc[mt][nt2] = __builtin_amdgcn_mfma_f32_16x16x32_bf16(ap, bv[nt2][kb2], oacc[mt][nt2], 0, 0, 0);
        }
    }

    __syncthreads();   // all PV done; head regions dead -> ao may overwrite

    // ---- attn-out (bf16) to ao (pitch 136, offset 0) ----
    #pragma unroll
    for (int mt = 0; mt < 4; ++mt)
        #pragma unroll
        for (int nt2 = 0; nt2 < 2; ++nt2)
            #pragma unroll
            for (int r = 0; r < 4; ++r) {
                const int row = mt * 16 + quad * 4 + r;
                smem[row * XP + h * 32 + nt2 * 16 + lid] =
                    (short)f2bf(oacc[mt][nt2][r] * invs[mt][r]);
            }
    __syncthreads();

    // ---- proj: wave h -> cols [32h, 32h+32) ----
    bf16x8 aa[4][4];
    #pragma unroll
    for (int mt = 0; mt < 4; ++mt)
        #pragma unroll
        for (int kb = 0; kb < 4; ++kb)
            aa[mt][kb] = *(const bf16x8*)&smem[(mt * 16 + lid) * XP + kb * 32 + quad * 8];

    float* outb = out + (size_t)b * 6272;
    #pragma unroll
    for (int nt = 0; nt < 2; ++nt) {
        const int cb = h * 32 + nt * 16;
        const unsigned short* wr = wbf + 49152 + (size_t)(cb + lid) * 128 + quad * 8;
        floatx4 acc[4] = {z4, z4, z4, z4};
        #pragma unroll
        for (int kb = 0; kb < 4; ++kb) {
            bf16x8 bw = *(const bf16x8*)(wr + kb * 32);
            #pragma unroll
            for (int mt = 0; mt < 4; ++mt)
                acc[mt] = __builtin_amdgcn_mfma_f32_16x16x32_bf16(aa[mt][kb], bw, acc[mt], 0, 0, 0);
        }
        const float pb = proj_b[cb + lid];
        #pragma unroll
        for (int mt = 0; mt < 4; ++mt)
            #pragma unroll
            for (int r = 0; r < 4; ++r) {
                const int row = mt * 16 + quad * 4 + r;
                if (row < 49)
                    outb[row * 128 + cb + lid] = acc[mt][r] + pb;
            }
    }
}

extern "C" void kernel_launch(void* const* d_in, const int* in_sizes, int n_in,
                              void* d_out, int out_size, void* d_ws, size_t ws_size,
                              hipStream_t stream) {
    (void)in_sizes; (void)n_in; (void)out_size; (void)ws_size;
    const float* x          = (const float*)d_in[0];
    const float* mask       = (const float*)d_in[1];
    const float* qkv_w      = (const float*)d_in[2];
    const float* qkv_b      = (const float*)d_in[3];
    const float* proj_w     = (const float*)d_in[4];
    const float* proj_b     = (const float*)d_in[5];
    const float* bias_table = (const float*)d_in[6];

    unsigned short* wbf = (unsigned short*)d_ws;                 // 131072 B
    float* cm           = (float*)((char*)d_ws + 131072);        // 2,458,624 B

    prep_kernel<<<3200, 256, 0, stream>>>(qkv_w, proj_w, bias_table, mask, wbf, cm);
    winattn_mfma<<<4096, 256, 0, stream>>>(x, qkv_b, proj_b, wbf, cm, (float*)d_out);
}